// Round 2
// baseline (83.539 us; speedup 1.0000x reference)
//
#include <hip/hip_runtime.h>

#define BB 8
#define NC 12
#define NC1 11
#define HH 512
#define WW 512
#define NG 64      // 8-h groups per column
#define GH 8       // h per group

static constexpr size_t CH = (size_t)HH * WW;   // 262144

// output offsets (flat floats, in return order)
static constexpr size_t OFF_LSM   = 0;
static constexpr size_t OFF_CLP   = (size_t)BB * NC1 * CH;                 // 23068672
static constexpr size_t OFF_CLEAN = OFF_CLP + (size_t)BB * NC1 * WW;       // 23113728
static constexpr size_t OFF_STD   = OFF_CLEAN + (size_t)BB * NC * CH;      // 48279552
static constexpr size_t OFF_TOPO  = OFF_STD + (size_t)BB * NC1 * WW;
static constexpr size_t OFF_CONT  = OFF_TOPO + (size_t)BB * (NC1 - 1) * WW;
static constexpr size_t OFF_CURV  = OFF_CONT + (size_t)BB * NC1 * (WW - 1);

// workspace layout (floats)
static constexpr size_t WS_BASE = 0;                                   // [88][64][512] normalized cum bases
static constexpr size_t WS_INV  = WS_BASE + (size_t)BB * NC1 * NG * WW; // [88][512]
static constexpr size_t WS_LOG  = WS_INV + (size_t)BB * NC1 * WW;
static constexpr size_t WS_LP   = WS_LOG + (size_t)BB * NC1 * WW;
// total ~12.1 MB

// ---------------------------------------------------------------- KA: per-column stats (fused K1+K2)
// block: 256 threads = 64 lanes (float2 -> 128 w) x 4 h-quarters; grid (4 wtiles, 11 c, 8 b)
__global__ __launch_bounds__(256) void ka_stats(const float* __restrict__ in,
                                                float* __restrict__ ws,
                                                float* __restrict__ out) {
    const int tx = threadIdx.x & 63;       // lane within wave
    const int ty = threadIdx.x >> 6;       // h-quarter 0..3
    const int wt = blockIdx.x;             // 0..3 (128-w tiles)
    const int c  = blockIdx.y;             // 0..10
    const int b  = blockIdx.z;             // 0..7
    const int w  = wt * 128 + tx * 2;
    const int bc = b * NC1 + c;

    __shared__ float lE[NG][128];          // per-8h group sums, per w
    __shared__ float lP[4][128];
    __shared__ float lQ[4][128];

    const float* p = in + (size_t)(b * NC + c) * CH + (size_t)(ty * 128) * WW + w;
    float Px = 0.f, Py = 0.f, Qx = 0.f, Qy = 0.f;
    for (int gl = 0; gl < 16; ++gl) {
        float Ex = 0.f, Ey = 0.f, P8x = 0.f, P8y = 0.f, Q8x = 0.f, Q8y = 0.f;
        const float hbase = (float)(ty * 128 + gl * 8);
#pragma unroll
        for (int i = 0; i < GH; ++i) {
            float2 x = *(const float2*)(p + (size_t)(gl * 8 + i) * WW);
            float ex = expf(x.x), ey = expf(x.y);
            float h = hbase + (float)i;
            Ex += ex; Ey += ey;
            P8x += h * ex; P8y += h * ey;
            Q8x += h * h * ex; Q8y += h * h * ey;
        }
        *(float2*)&lE[ty * 16 + gl][tx * 2] = make_float2(Ex, Ey);
        Px += P8x; Py += P8y;
        Qx += Q8x; Qy += Q8y;
    }
    *(float2*)&lP[ty][tx * 2] = make_float2(Px, Py);
    *(float2*)&lQ[ty][tx * 2] = make_float2(Qx, Qy);
    __syncthreads();
    if (ty != 0) return;

    // per-w (float2) totals + prefix bases
    float Sx = 0.f, Sy = 0.f;
#pragma unroll
    for (int g = 0; g < NG; ++g) {
        float2 e = *(const float2*)&lE[g][tx * 2];
        Sx += e.x; Sy += e.y;
    }
    const float invx = 1.f / Sx, invy = 1.f / Sy;
    float rx = 0.f, ry = 0.f;
    float* bp = ws + WS_BASE + (size_t)bc * NG * WW + w;
#pragma unroll
    for (int g = 0; g < NG; ++g) {
        *(float2*)(bp + (size_t)g * WW) = make_float2(rx * invx, ry * invy);
        float2 e = *(const float2*)&lE[g][tx * 2];
        rx += e.x; ry += e.y;
    }
    float Ptx = lP[0][tx*2] + lP[1][tx*2] + lP[2][tx*2] + lP[3][tx*2];
    float Pty = lP[0][tx*2+1] + lP[1][tx*2+1] + lP[2][tx*2+1] + lP[3][tx*2+1];
    float Qtx = lQ[0][tx*2] + lQ[1][tx*2] + lQ[2][tx*2] + lQ[3][tx*2];
    float Qty = lQ[0][tx*2+1] + lQ[1][tx*2+1] + lQ[2][tx*2+1] + lQ[3][tx*2+1];
    float lpx = Ptx * invx, lpy = Pty * invy;
    float vx = Qtx * invx - lpx * lpx; if (vx < 0.f) vx = 0.f;
    float vy = Qty * invy - lpy * lpy; if (vy < 0.f) vy = 0.f;

    const size_t o = (size_t)bc * WW + w;
    *(float2*)(ws + WS_INV + o) = make_float2(invx, invy);
    *(float2*)(ws + WS_LOG + o) = make_float2(logf(Sx), logf(Sy));
    *(float2*)(ws + WS_LP + o)  = make_float2(lpx, lpy);
    *(float2*)(out + OFF_STD + o) = make_float2(sqrtf(vx), sqrtf(vy));
}

// ---------------------------------------------------------------- KB: lsm + clean_masks (+ smalls on g==0)
// block: 256 threads x float2 = 512 w; grid (64 h-groups, 8 b)
__global__ __launch_bounds__(256) void kb_emit(const float* __restrict__ in,
                                               const float* __restrict__ ws,
                                               float* __restrict__ out) {
    const int t = threadIdx.x;
    const int g = blockIdx.x;   // 0..63
    const int b = blockIdx.y;   // 0..7
    const int w = t * 2;

    float2 cum[NC1], inv[NC1], lgs[NC1];
#pragma unroll
    for (int c = 0; c < NC1; ++c) {
        const size_t bc = (size_t)(b * NC1 + c);
        cum[c] = *(const float2*)(ws + WS_BASE + (bc * NG + g) * WW + w);
        inv[c] = *(const float2*)(ws + WS_INV + bc * WW + w);
        lgs[c] = *(const float2*)(ws + WS_LOG + bc * WW + w);
    }
    const float* ip  = in + (size_t)b * NC * CH + (size_t)(g * GH) * WW + w;
    float* lsm = out + OFF_LSM + (size_t)b * NC1 * CH + (size_t)(g * GH) * WW + w;
    float* cln = out + OFF_CLEAN + (size_t)b * NC * CH + (size_t)(g * GH) * WW + w;

    for (int i = 0; i < GH; ++i) {
        const size_t ho = (size_t)i * WW;
        float2 x[NC1];
#pragma unroll
        for (int c = 0; c < NC1; ++c)
            x[c] = *(const float2*)(ip + (size_t)c * CH + ho);
#pragma unroll
        for (int c = 0; c < NC1; ++c) {
            cum[c].x += expf(x[c].x) * inv[c].x;
            cum[c].y += expf(x[c].y) * inv[c].y;
            *(float2*)(lsm + (size_t)c * CH + ho) =
                make_float2(x[c].x - lgs[c].x, x[c].y - lgs[c].y);
        }
        float2 tc = cum[0];
        *(float2*)(cln + ho) = make_float2(1.f - tc.x, 1.f - tc.y);
#pragma unroll
        for (int k = 1; k < NC1; ++k) {
            float2 t2 = make_float2(fmaxf(cum[k].x + tc.x - 1.f, 0.f),
                                    fmaxf(cum[k].y + tc.y - 1.f, 0.f));
            *(float2*)(cln + (size_t)k * CH + ho) = make_float2(tc.x - t2.x, tc.y - t2.y);
            tc = t2;
        }
        *(float2*)(cln + (size_t)NC1 * CH + ho) = tc;
    }

    if (g != 0) return;
    // ---- smalls (former K3): cummax / topology / continuity / curvature from lp
    const float CM[NC1] = {1.2261f, 1.1558f, 1.1161f, 1.1195f, 2.7202f, 2.3714f,
                           1.7055f, 3.2717f, 2.6716f, 5.0418f, 0.4293f};
    const float* lp = ws + WS_LP;
#pragma unroll
    for (int s = 0; s < 2; ++s) {
        const int wv = w + s;
        const int wm = (wv - 5 < 0) ? 0 : wv - 5;
        const int wp = (wv + 5 > WW - 1) ? WW - 1 : wv + 5;
        float m = 0.f, prev = 0.f;
        for (int c = 0; c < NC1; ++c) {
            const size_t rb = (size_t)(b * NC1 + c) * WW;
            const float lv = lp[rb + wv];
            m = (c == 0) ? lv : fmaxf(m, lv);
            out[OFF_CLP + rb + wv] = m;
            if (c > 0)
                out[OFF_TOPO + (size_t)(b * (NC1 - 1) + (c - 1)) * WW + wv] =
                    fmaxf(prev - lv, 0.f);
            prev = lv;
            if (wv < WW - 1) {
                const float nxt = lp[rb + wv + 1];
                out[OFF_CONT + (size_t)(b * NC1 + c) * (WW - 1) + wv] = fabsf(lv - nxt);
            }
            const float a  = lp[rb + wm];
            const float bb = lp[rb + wp];
            const float fo = bb - a;
            const float so = a - 2.f * lv + bb;
            const float bs = 1.f + fo * fo;
            out[OFF_CURV + rb + wv] = fabsf(so / (bs * sqrtf(bs))) - CM[c];
        }
    }
}

extern "C" void kernel_launch(void* const* d_in, const int* in_sizes, int n_in,
                              void* d_out, int out_size, void* d_ws, size_t ws_size,
                              hipStream_t stream) {
    const float* in = (const float*)d_in[0];
    float* out = (float*)d_out;
    float* ws = (float*)d_ws;

    hipLaunchKernelGGL(ka_stats, dim3(4, NC1, BB), dim3(256), 0, stream, in, ws, out);
    hipLaunchKernelGGL(kb_emit, dim3(NG, BB), dim3(256), 0, stream, in, ws, out);
}

// Round 3
// 81.308 us; speedup vs baseline: 1.0274x; 1.0274x over previous
//
#include <hip/hip_runtime.h>

#define BB 8
#define NC 12
#define NC1 11
#define HH 512
#define WW 512
#define NCH 32     // 16-h chunks per column
#define HC 16
#define WT 32      // w per KS block
#define XLD 34     // padded LDS leading dim

static constexpr size_t CH = (size_t)HH * WW;   // 262144

// output offsets (flat floats, in return order)
static constexpr size_t OFF_LSM   = 0;
static constexpr size_t OFF_CLP   = (size_t)BB * NC1 * CH;                 // 23068672
static constexpr size_t OFF_CLEAN = OFF_CLP + (size_t)BB * NC1 * WW;       // 23113728
static constexpr size_t OFF_STD   = OFF_CLEAN + (size_t)BB * NC * CH;      // 48279552
static constexpr size_t OFF_TOPO  = OFF_STD + (size_t)BB * NC1 * WW;
static constexpr size_t OFF_CONT  = OFF_TOPO + (size_t)BB * (NC1 - 1) * WW;
static constexpr size_t OFF_CURV  = OFF_CONT + (size_t)BB * NC1 * (WW - 1);

// workspace (floats)
static constexpr size_t WS_BASE = 0;                                    // [88][32][512] normalized cum bases
static constexpr size_t WS_LP   = WS_BASE + (size_t)BB * NC1 * NCH * WW; // [88][512]

// ---------------------------------------------------------------- KS: stats + lsm + bases + std
// grid (16 wtiles, 11 c, 8 b), 512 threads, ~78KB LDS -> 2 blocks/CU
__global__ __launch_bounds__(512) void ks_stats(const float* __restrict__ in,
                                                float* __restrict__ ws,
                                                float* __restrict__ out) {
    const int t  = threadIdx.x;
    const int wt = blockIdx.x, c = blockIdx.y, b = blockIdx.z;
    const int bc = b * NC1 + c;
    const int w0 = wt * WT;

    __shared__ float xs[HH][XLD];      // 69632 B (padded: +2 banks/row)
    __shared__ float cs[NCH][WT];      // 16-h chunk sums -> normalized bases
    __shared__ float pP[16][WT];
    __shared__ float pQ[16][WT];
    __shared__ float lgS[WT];

    // phase 1: global -> LDS (float2, 4 rows x 128B per wave instr)
    {
        const int w2 = t & 15, r = t >> 4;   // r 0..31
        const float* p = in + (size_t)(b * NC + c) * CH + (size_t)r * WW + w0 + 2 * w2;
#pragma unroll
        for (int i = 0; i < 16; ++i) {
            float2 v = *(const float2*)(p + (size_t)(i * 32) * WW);
            xs[r + 32 * i][2 * w2]     = v.x;
            xs[r + 32 * i][2 * w2 + 1] = v.y;
        }
    }
    __syncthreads();

    // phase 2: per-(w, 32-h slab) partial E (per 16-h chunk), P, Q
    {
        const int w = t & 31, q = t >> 5;    // q 0..15 covers h [32q, 32q+32)
        float P = 0.f, Q = 0.f;
#pragma unroll
        for (int j = 0; j < 2; ++j) {
            float E = 0.f;
#pragma unroll
            for (int i = 0; i < HC; ++i) {
                const int h = q * 32 + j * HC + i;
                const float e = expf(xs[h][w]);
                const float hf = (float)h;
                E += e; P += hf * e; Q += hf * hf * e;
            }
            cs[q * 2 + j][w] = E;
        }
        pP[q][w] = P; pQ[q][w] = Q;
    }
    __syncthreads();

    // phase 3: per-w totals, prefix bases, stats (one lane per w)
    if (t < WT) {
        const int w = t;
        float S = 0.f;
#pragma unroll
        for (int ch = 0; ch < NCH; ++ch) S += cs[ch][w];
        const float inv = 1.f / S;
        float run = 0.f;
#pragma unroll
        for (int ch = 0; ch < NCH; ++ch) {
            const float e = cs[ch][w];
            cs[ch][w] = run * inv;           // normalized cumsum BEFORE chunk
            run += e;
        }
        float P = 0.f, Q = 0.f;
#pragma unroll
        for (int q = 0; q < 16; ++q) { P += pP[q][w]; Q += pQ[q][w]; }
        const float lp = P * inv;
        float var = Q * inv - lp * lp; if (var < 0.f) var = 0.f;
        lgS[w] = logf(S);
        const size_t o = (size_t)bc * WW + w0 + w;
        ws[WS_LP + o] = lp;
        out[OFF_STD + o] = sqrtf(var);
    }
    __syncthreads();

    // phase 4a: bases -> ws
    {
        const int w = t & 31, chg = t >> 5;  // 16 groups x 2 chunks
#pragma unroll
        for (int j = 0; j < 2; ++j) {
            const int ch = chg * 2 + j;
            ws[WS_BASE + ((size_t)bc * NCH + ch) * WW + w0 + w] = cs[ch][w];
        }
    }
    // phase 4b: lsm = x - logS from LDS-resident tile
    {
        const int w2 = t & 15, r = t >> 4;
        const float l0 = lgS[2 * w2], l1 = lgS[2 * w2 + 1];
        float* lo = out + OFF_LSM + (size_t)bc * CH + (size_t)r * WW + w0 + 2 * w2;
#pragma unroll
        for (int i = 0; i < 16; ++i) {
            const int h = r + 32 * i;
            float2 v = make_float2(xs[h][2 * w2] - l0, xs[h][2 * w2 + 1] - l1);
            *(float2*)(lo + (size_t)(i * 32) * WW) = v;
        }
    }
}

// ---------------------------------------------------------------- KC: clean_masks (+ smalls on chunk==0)
// grid (2 whalf, 32 chunk, 8 b), 256 threads
__global__ __launch_bounds__(256) void kc_clean(const float* __restrict__ ws,
                                                float* __restrict__ out) {
    const int t = threadIdx.x;
    const int wh = blockIdx.x, chunk = blockIdx.y, b = blockIdx.z;
    const int w = wh * 256 + t;

    float cum[NC1];
#pragma unroll
    for (int c = 0; c < NC1; ++c)
        cum[c] = ws[WS_BASE + (((size_t)(b * NC1 + c)) * NCH + chunk) * WW + w];

    const float* lsm = out + OFF_LSM + (size_t)b * NC1 * CH + (size_t)(chunk * HC) * WW + w;
    float* cln = out + OFF_CLEAN + (size_t)b * NC * CH + (size_t)(chunk * HC) * WW + w;

    for (int i = 0; i < HC; ++i) {
        const size_t ho = (size_t)i * WW;
        float s[NC1];
#pragma unroll
        for (int c = 0; c < NC1; ++c)
            s[c] = expf(lsm[(size_t)c * CH + ho]);   // sm = exp(log_softmax)
#pragma unroll
        for (int c = 0; c < NC1; ++c)
            cum[c] += s[c];
        float tc = cum[0];
        cln[ho] = 1.f - tc;
#pragma unroll
        for (int k = 1; k < NC1; ++k) {
            const float t2 = fmaxf(cum[k] + tc - 1.f, 0.f);
            cln[(size_t)k * CH + ho] = tc - t2;
            tc = t2;
        }
        cln[(size_t)NC1 * CH + ho] = tc;
    }

    if (chunk != 0) return;
    // ---- smalls: cummax / topology / continuity / curvature from lp
    const float CM[NC1] = {1.2261f, 1.1558f, 1.1161f, 1.1195f, 2.7202f, 2.3714f,
                           1.7055f, 3.2717f, 2.6716f, 5.0418f, 0.4293f};
    const float* lp = ws + WS_LP;
    const int wm = (w - 5 < 0) ? 0 : w - 5;
    const int wp = (w + 5 > WW - 1) ? WW - 1 : w + 5;
    float m = 0.f, prev = 0.f;
    for (int c = 0; c < NC1; ++c) {
        const size_t rb = (size_t)(b * NC1 + c) * WW;
        const float lv = lp[rb + w];
        m = (c == 0) ? lv : fmaxf(m, lv);
        out[OFF_CLP + rb + w] = m;
        if (c > 0)
            out[OFF_TOPO + (size_t)(b * (NC1 - 1) + (c - 1)) * WW + w] = fmaxf(prev - lv, 0.f);
        prev = lv;
        if (w < WW - 1) {
            const float nxt = lp[rb + w + 1];
            out[OFF_CONT + (size_t)(b * NC1 + c) * (WW - 1) + w] = fabsf(lv - nxt);
        }
        const float a  = lp[rb + wm];
        const float bb = lp[rb + wp];
        const float fo = bb - a;
        const float so = a - 2.f * lv + bb;
        const float bs = 1.f + fo * fo;
        out[OFF_CURV + rb + w] = fabsf(so / (bs * sqrtf(bs))) - CM[c];
    }
}

extern "C" void kernel_launch(void* const* d_in, const int* in_sizes, int n_in,
                              void* d_out, int out_size, void* d_ws, size_t ws_size,
                              hipStream_t stream) {
    const float* in = (const float*)d_in[0];
    float* out = (float*)d_out;
    float* ws = (float*)d_ws;

    hipLaunchKernelGGL(ks_stats, dim3(16, NC1, BB), dim3(512), 0, stream, in, ws, out);
    hipLaunchKernelGGL(kc_clean, dim3(2, NCH, BB), dim3(256), 0, stream, ws, out);
}